// Round 2
// baseline (251.697 us; speedup 1.0000x reference)
//
#include <hip/hip_runtime.h>
#include <cstddef>

#define NCAPS  10
#define BATCH  256
#define NROUTE 1152
#define CIN    8
#define COUT   16
#define T      384          // threads per block (6 waves)
#define RPT    3            // routes per thread: 1152/384
#define NB     2            // batch elements per block
#define NWAVE  (T / 64)
#define NBLK   (NCAPS * (BATCH / NB))   // 1280 blocks

// full-wave scalar sum
__device__ __forceinline__ float wave_sum(float v) {
    v += __shfl_xor(v, 1);  v += __shfl_xor(v, 2);  v += __shfl_xor(v, 4);
    v += __shfl_xor(v, 8);  v += __shfl_xor(v, 16); v += __shfl_xor(v, 32);
    return v;
}

// Component-splitting butterfly: reduces s[0..15] over the 64 lanes.
// On return, lane L (L<16) holds the wave-total of component
// comp(L) = ((L&1)<<3)|((L&2)<<1)|((L&4)>>1)|((L&8)>>3) in s[0].
__device__ __forceinline__ float wave_sum16(float* s, int lane) {
#pragma unroll
    for (int j = 0; j < 8; ++j) {
        float snd = (lane & 1) ? s[j] : s[j + 8];
        float r = __shfl_xor(snd, 1);
        s[j] = ((lane & 1) ? s[j + 8] : s[j]) + r;
    }
#pragma unroll
    for (int j = 0; j < 4; ++j) {
        float snd = (lane & 2) ? s[j] : s[j + 4];
        float r = __shfl_xor(snd, 2);
        s[j] = ((lane & 2) ? s[j + 4] : s[j]) + r;
    }
#pragma unroll
    for (int j = 0; j < 2; ++j) {
        float snd = (lane & 4) ? s[j] : s[j + 2];
        float r = __shfl_xor(snd, 4);
        s[j] = ((lane & 4) ? s[j + 2] : s[j]) + r;
    }
    {
        float snd = (lane & 8) ? s[0] : s[1];
        float r = __shfl_xor(snd, 8);
        s[0] = ((lane & 8) ? s[1] : s[0]) + r;
    }
    s[0] += __shfl_xor(s[0], 16);
    s[0] += __shfl_xor(s[0], 32);
    return s[0];
}

// launch_bounds min-occupancy arg = 1: do NOT cap VGPRs at 128 (round-1 spill
// bug: (384,2) capped allocator at 128 VGPR -> ~100 floats/thread spilled ->
// 378 MB of HBM scratch traffic -> 206 us).
__global__ __launch_bounds__(T, 1) void caps_routing(const float* __restrict__ x,
                                                     const float* __restrict__ W,
                                                     float* __restrict__ out) {
    __shared__ float sred[NWAVE][NB][20];   // [wave][b][comp 0..15, 16=sumE]
    __shared__ float outLDS[NB][COUT];

    const int tid  = threadIdx.x;
    const int lane = tid & 63;
    const int wv   = tid >> 6;

    // XCD-aware swizzle: consecutive-mod-8 blocks (same XCD) get contiguous
    // work -> each XCD touches ~1.25 capsules, W[c] (590KB) stays in its 4MB L2.
    int g    = blockIdx.x;
    int widx = (g & 7) * (NBLK / 8) + (g >> 3);   // bijective, 1280 % 8 == 0
    int c    = widx >> 7;                          // / (BATCH/NB = 128)
    int b0   = (widx & 127) * NB;

    const float* Wc  = W + (size_t)c * (NROUTE * CIN * COUT);
    const float* xp0 = x + (size_t)b0 * (NROUTE * CIN);
    const float* xp1 = xp0 + NROUTE * CIN;

    // priors in registers: pr[b][k][o], thread owns routes r = tid + k*T
    float pr[NB][RPT][COUT];

    // ---------------- Phase A: priors = x . W (accumulate directly into pr) --
#pragma unroll
    for (int k = 0; k < RPT; ++k) {
        const int r = tid + k * T;
        const float4* wp  = reinterpret_cast<const float4*>(Wc + (size_t)r * (CIN * COUT));
        const float4* xq0 = reinterpret_cast<const float4*>(xp0 + r * CIN);
        const float4* xq1 = reinterpret_cast<const float4*>(xp1 + r * CIN);
        float4 xa = xq0[0], xb = xq0[1];
        float4 ya = xq1[0], yb = xq1[1];
        float xs0[8] = {xa.x, xa.y, xa.z, xa.w, xb.x, xb.y, xb.z, xb.w};
        float xs1[8] = {ya.x, ya.y, ya.z, ya.w, yb.x, yb.y, yb.z, yb.w};
#pragma unroll
        for (int o = 0; o < COUT; ++o) { pr[0][k][o] = 0.f; pr[1][k][o] = 0.f; }
#pragma unroll
        for (int i = 0; i < CIN; ++i) {
            const float xi = xs0[i];
            const float yi = xs1[i];
#pragma unroll
            for (int j = 0; j < 4; ++j) {
                float4 w4 = wp[i * 4 + j];
                pr[0][k][4 * j + 0] = fmaf(xi, w4.x, pr[0][k][4 * j + 0]);
                pr[0][k][4 * j + 1] = fmaf(xi, w4.y, pr[0][k][4 * j + 1]);
                pr[0][k][4 * j + 2] = fmaf(xi, w4.z, pr[0][k][4 * j + 2]);
                pr[0][k][4 * j + 3] = fmaf(xi, w4.w, pr[0][k][4 * j + 3]);
                pr[1][k][4 * j + 0] = fmaf(yi, w4.x, pr[1][k][4 * j + 0]);
                pr[1][k][4 * j + 1] = fmaf(yi, w4.y, pr[1][k][4 * j + 1]);
                pr[1][k][4 * j + 2] = fmaf(yi, w4.z, pr[1][k][4 * j + 2]);
                pr[1][k][4 * j + 3] = fmaf(yi, w4.w, pr[1][k][4 * j + 3]);
            }
        }
    }

    // ---------------- Phase B: 3 routing iterations ----------------
    float l[NB][RPT];
#pragma unroll
    for (int b = 0; b < NB; ++b)
#pragma unroll
        for (int k = 0; k < RPT; ++k) l[b][k] = 0.f;

    const int comp = ((lane & 1) << 3) | ((lane & 2) << 1) | ((lane & 4) >> 1) | ((lane & 8) >> 3);

    for (int it = 0; it < 3; ++it) {
        // b-outer loop: only one batch's og/s16/se live at a time (reg pressure)
#pragma unroll
        for (int b = 0; b < NB; ++b) {
            float og[COUT];
            if (it > 0) {
#pragma unroll
                for (int o = 0; o < COUT; ++o) og[o] = outLDS[b][o];
            }
            float s16[COUT];
            float se = 0.f;
#pragma unroll
            for (int o = 0; o < COUT; ++o) s16[o] = 0.f;

#pragma unroll
            for (int k = 0; k < RPT; ++k) {
                if (it > 0) {
                    float d = 0.f;
#pragma unroll
                    for (int o = 0; o < COUT; ++o) d = fmaf(pr[b][k][o], og[o], d);
                    l[b][k] += d;
                }
                const float e = __expf(l[b][k]);   // logits bounded ~|45|, no max-sub needed
                se += e;
#pragma unroll
                for (int o = 0; o < COUT; ++o) s16[o] = fmaf(e, pr[b][k][o], s16[o]);
            }

            const float sv  = wave_sum16(s16, lane);
            const float sev = wave_sum(se);
            if (lane < 16) sred[wv][b][comp] = sv;
            if (lane == 0) sred[wv][b][16]   = sev;
        }
        __syncthreads();

        if (tid < 32) {
            const int b = tid >> 4, o = tid & 15;
            float S = 0.f, SE = 0.f;
#pragma unroll
            for (int w2 = 0; w2 < NWAVE; ++w2) {
                S  += sred[w2][b][o];
                SE += sred[w2][b][16];
            }
            const float tt = S / SE;
            float p = tt * tt;
            p += __shfl_xor(p, 1); p += __shfl_xor(p, 2);
            p += __shfl_xor(p, 4); p += __shfl_xor(p, 8);   // p = |s|^2 within 16-lane group
            const float scale = p / ((1.f + p) * sqrtf(p));
            const float val = tt * scale;
            outLDS[b][o] = val;
            if (it == 2) out[((size_t)c * BATCH + b0 + b) * COUT + o] = val;
        }
        __syncthreads();
    }
}

extern "C" void kernel_launch(void* const* d_in, const int* in_sizes, int n_in,
                              void* d_out, int out_size, void* d_ws, size_t ws_size,
                              hipStream_t stream) {
    const float* x = (const float*)d_in[0];
    const float* w = (const float*)d_in[1];
    float* out = (float*)d_out;
    hipLaunchKernelGGL(caps_routing, dim3(NBLK), dim3(T), 0, stream, x, w, out);
}

// Round 3
// 185.673 us; speedup vs baseline: 1.3556x; 1.3556x over previous
//
#include <hip/hip_runtime.h>
#include <cstddef>

#define NCAPS  10
#define BATCH  256
#define NROUTE 1152
#define CIN    8
#define COUT   16
#define T      768          // threads per block (12 waves)
#define RPT    3            // (route, half) units per thread: 1152*2/768
#define NB     2            // batch elements per block
#define NWAVE  (T / 64)
#define NBLK   (NCAPS * (BATCH / NB))   // 1280 blocks

// full-wave scalar sum (note: pair-duplicated inputs give exactly 2x the true sum)
__device__ __forceinline__ float wave_sum(float v) {
    v += __shfl_xor(v, 1);  v += __shfl_xor(v, 2);  v += __shfl_xor(v, 4);
    v += __shfl_xor(v, 8);  v += __shfl_xor(v, 16); v += __shfl_xor(v, 32);
    return v;
}

// Component-splitting butterfly over 8 components held per-lane, reducing
// across the 64 lanes with masks {2,4,8} then scalar {16,32}. On return,
// lane L holds in s[0] the wave-total of component
//   comp(L) = 4*((L>>1)&1) + 2*((L>>2)&1) + ((L>>3)&1)
// summed over all lanes with the same parity-class component set.
__device__ __forceinline__ float wave_sum8(float* s, int lane) {
#pragma unroll
    for (int j = 0; j < 4; ++j) {
        float snd = (lane & 2) ? s[j] : s[j + 4];
        float r = __shfl_xor(snd, 2);
        s[j] = ((lane & 2) ? s[j + 4] : s[j]) + r;
    }
#pragma unroll
    for (int j = 0; j < 2; ++j) {
        float snd = (lane & 4) ? s[j] : s[j + 2];
        float r = __shfl_xor(snd, 4);
        s[j] = ((lane & 4) ? s[j + 2] : s[j]) + r;
    }
    {
        float snd = (lane & 8) ? s[0] : s[1];
        float r = __shfl_xor(snd, 8);
        s[0] = ((lane & 8) ? s[1] : s[0]) + r;
    }
    s[0] += __shfl_xor(s[0], 16);
    s[0] += __shfl_xor(s[0], 32);
    return s[0];
}

// Half-row-per-thread design: thread t owns routes r = (t>>1) + k*384 and
// output half h = t&1 (8 of 16 outs). Per-thread priors = 2*3*8 = 48 floats,
// total regs ~100 -> fits the 128-VGPR allocation the backend insists on
// (rounds 1-2: 170-reg working set spilled ~400 MB of scratch HBM traffic).
__global__ __launch_bounds__(T, 3) void caps_routing(const float* __restrict__ x,
                                                     const float* __restrict__ W,
                                                     float* __restrict__ out) {
    __shared__ float sred[NWAVE][NB][20];   // [wave][b][comp 0..15, 16=sumExp]
    __shared__ float outLDS[NB][COUT];

    const int tid  = threadIdx.x;
    const int lane = tid & 63;
    const int wv   = tid >> 6;
    const int h    = tid & 1;        // output half
    const int rb   = tid >> 1;       // route base 0..383

    // XCD-aware swizzle: each XCD sees a contiguous widx range -> touches <=2
    // capsules -> W[c] (590KB x 2) stays in its 4MB L2.
    int g    = blockIdx.x;
    int widx = (g & 7) * (NBLK / 8) + (g >> 3);   // bijective, 1280 % 8 == 0
    int c    = widx >> 7;                          // / (BATCH/NB = 128)
    int b0   = (widx & 127) * NB;

    const float* Wc  = W + (size_t)c * (NROUTE * CIN * COUT);
    const float* xp0 = x + (size_t)b0 * (NROUTE * CIN);
    const float* xp1 = xp0 + NROUTE * CIN;

    float pr[NB][RPT][8];

    // ---------------- Phase A: priors = x . W (half-row per thread) --------
#pragma unroll
    for (int k = 0; k < RPT; ++k) {
        const int r = rb + k * (T / 2);
        const float4* wp  = reinterpret_cast<const float4*>(Wc + (size_t)r * (CIN * COUT) + h * 8);
        const float4* xq0 = reinterpret_cast<const float4*>(xp0 + r * CIN);
        const float4* xq1 = reinterpret_cast<const float4*>(xp1 + r * CIN);
        float4 xa = xq0[0], xb = xq0[1];
        float4 ya = xq1[0], yb = xq1[1];
        float xs0[8] = {xa.x, xa.y, xa.z, xa.w, xb.x, xb.y, xb.z, xb.w};
        float xs1[8] = {ya.x, ya.y, ya.z, ya.w, yb.x, yb.y, yb.z, yb.w};
#pragma unroll
        for (int j = 0; j < 8; ++j) { pr[0][k][j] = 0.f; pr[1][k][j] = 0.f; }
#pragma unroll
        for (int i = 0; i < CIN; ++i) {
            const float xi = xs0[i];
            const float yi = xs1[i];
            float4 wA = wp[i * 4];       // W[r][i][h*8 .. h*8+3]
            float4 wB = wp[i * 4 + 1];   // W[r][i][h*8+4 .. h*8+7]
            pr[0][k][0] = fmaf(xi, wA.x, pr[0][k][0]);
            pr[0][k][1] = fmaf(xi, wA.y, pr[0][k][1]);
            pr[0][k][2] = fmaf(xi, wA.z, pr[0][k][2]);
            pr[0][k][3] = fmaf(xi, wA.w, pr[0][k][3]);
            pr[0][k][4] = fmaf(xi, wB.x, pr[0][k][4]);
            pr[0][k][5] = fmaf(xi, wB.y, pr[0][k][5]);
            pr[0][k][6] = fmaf(xi, wB.z, pr[0][k][6]);
            pr[0][k][7] = fmaf(xi, wB.w, pr[0][k][7]);
            pr[1][k][0] = fmaf(yi, wA.x, pr[1][k][0]);
            pr[1][k][1] = fmaf(yi, wA.y, pr[1][k][1]);
            pr[1][k][2] = fmaf(yi, wA.z, pr[1][k][2]);
            pr[1][k][3] = fmaf(yi, wA.w, pr[1][k][3]);
            pr[1][k][4] = fmaf(yi, wB.x, pr[1][k][4]);
            pr[1][k][5] = fmaf(yi, wB.y, pr[1][k][5]);
            pr[1][k][6] = fmaf(yi, wB.z, pr[1][k][6]);
            pr[1][k][7] = fmaf(yi, wB.w, pr[1][k][7]);
        }
    }

    // ---------------- Phase B: 3 routing iterations ----------------
    float l[NB][RPT];
#pragma unroll
    for (int b = 0; b < NB; ++b)
#pragma unroll
        for (int k = 0; k < RPT; ++k) l[b][k] = 0.f;

    for (int it = 0; it < 3; ++it) {
#pragma unroll
        for (int b = 0; b < NB; ++b) {
            float og8[8];
            if (it > 0) {
#pragma unroll
                for (int j = 0; j < 8; ++j) og8[j] = outLDS[b][h * 8 + j];
            }
            float s8[8];
            float se = 0.f;
#pragma unroll
            for (int j = 0; j < 8; ++j) s8[j] = 0.f;

#pragma unroll
            for (int k = 0; k < RPT; ++k) {
                if (it > 0) {
                    float d = 0.f;
#pragma unroll
                    for (int j = 0; j < 8; ++j) d = fmaf(pr[b][k][j], og8[j], d);
                    d += __shfl_xor(d, 1);   // combine halves -> full 16-dot
                    l[b][k] += d;
                }
                const float e = __expf(l[b][k]);   // logits bounded ~|45|
                se += e;
#pragma unroll
                for (int j = 0; j < 8; ++j) s8[j] = fmaf(e, pr[b][k][j], s8[j]);
            }

            const float sv  = wave_sum8(s8, lane);
            const float sev = wave_sum(se);   // pair-duplicated: exactly 2x true sum
            if (lane < 16) {
                const int o = (lane & 1) * 8 + 4 * ((lane >> 1) & 1)
                            + 2 * ((lane >> 2) & 1) + ((lane >> 3) & 1);
                sred[wv][b][o] = sv;
            }
            if (lane == 0) sred[wv][b][16] = sev * 0.5f;
        }
        __syncthreads();

        if (tid < 32) {
            const int b = tid >> 4, o = tid & 15;
            float S = 0.f, SE = 0.f;
#pragma unroll
            for (int w2 = 0; w2 < NWAVE; ++w2) {
                S  += sred[w2][b][o];
                SE += sred[w2][b][16];
            }
            const float tt = S / SE;
            float p = tt * tt;
            p += __shfl_xor(p, 1); p += __shfl_xor(p, 2);
            p += __shfl_xor(p, 4); p += __shfl_xor(p, 8);   // |s|^2 in 16-lane group
            const float scale = p / ((1.f + p) * sqrtf(p));
            const float val = tt * scale;
            outLDS[b][o] = val;
            if (it == 2) out[((size_t)c * BATCH + b0 + b) * COUT + o] = val;
        }
        __syncthreads();
    }
}

extern "C" void kernel_launch(void* const* d_in, const int* in_sizes, int n_in,
                              void* d_out, int out_size, void* d_ws, size_t ws_size,
                              hipStream_t stream) {
    const float* x = (const float*)d_in[0];
    const float* w = (const float*)d_in[1];
    float* out = (float*)d_out;
    hipLaunchKernelGGL(caps_routing, dim3(NBLK), dim3(T), 0, stream, x, w, out);
}